// Round 1
// baseline (280.005 us; speedup 1.0000x reference)
//
#include <hip/hip_runtime.h>
#include <math.h>

// Problem constants (fixed by the reference): D=U=E=128, T=20.
// N, V derived from in_sizes at launch.

// ---------------------------------------------------------------------------
// Generic fused row-GEMM:  out[r][c] = relu( (A[g(r)] @ W)[c] * scale + bias[c] )
//   A: [M x lda] fp32 (optionally gathered through gidx)
//   W: [K x 128] fp32 row-major
//   K in {128, 256}; 128x128 output tile per 256-thread block; 8x8 per thread.
//   Optional: SUMSQ -> per-block sum of squares of relu'd outputs (rows < M)
//             SCALE -> multiply accumulator by *scale_ptr before bias+relu
// ---------------------------------------------------------------------------
template<int K, bool GATHER, bool SUMSQ, bool SCALE>
__global__ __launch_bounds__(256, 2)
void gemm_relu(const float* __restrict__ A, int lda,
               const int* __restrict__ gidx,
               const float* __restrict__ W,
               const float* __restrict__ bias,
               float* __restrict__ out, int ldo, int M,
               float* __restrict__ partials,
               const float* __restrict__ scale_ptr)
{
    __shared__ float AT[64 * 128];   // A-chunk, transposed [kk][row], XOR-swizzled
    __shared__ float WT[64 * 128];   // W-chunk [kk][col]

    const int tid = threadIdx.x;
    const int tr  = tid >> 4;        // 0..15 -> rows 8*tr..8*tr+7
    const int tc  = tid & 15;        // 0..15 -> cols 4*tc..+3 and 64+4*tc..+3
    const int brow = blockIdx.x * 128;

    float acc[8][8];
#pragma unroll
    for (int i = 0; i < 8; ++i)
#pragma unroll
        for (int j = 0; j < 8; ++j) acc[i][j] = 0.f;

    for (int k0 = 0; k0 < K; k0 += 64) {
        // ---- stage A chunk (128 rows x 64 k), transposed into LDS ----
#pragma unroll
        for (int it = 0; it < 8; ++it) {
            int idx = it * 256 + tid;        // 0..2047
            int r   = idx >> 4;              // 0..127
            int q   = idx & 15;              // k-quad 0..15
            int row = brow + r;
            int grow = (row < M) ? row : (M - 1);
            if (GATHER) grow = gidx[grow];
            const float4 v = *reinterpret_cast<const float4*>(
                &A[(size_t)grow * lda + k0 + 4 * q]);
            const int rs = r ^ ((q & 7) << 2);   // swizzle rows to spread banks
            AT[(4 * q + 0) * 128 + rs] = v.x;
            AT[(4 * q + 1) * 128 + rs] = v.y;
            AT[(4 * q + 2) * 128 + rs] = v.z;
            AT[(4 * q + 3) * 128 + rs] = v.w;
        }
        // ---- stage W chunk (64 k x 128 cols) ----
#pragma unroll
        for (int it = 0; it < 8; ++it) {
            int idx = it * 256 + tid;        // 0..2047
            int kk  = idx >> 5;              // 0..63
            int cq  = idx & 31;              // 0..31
            *reinterpret_cast<float4*>(&WT[kk * 128 + 4 * cq]) =
                *reinterpret_cast<const float4*>(&W[(size_t)(k0 + kk) * 128 + 4 * cq]);
        }
        __syncthreads();

        // ---- compute ----
#pragma unroll 4
        for (int kk = 0; kk < 64; ++kk) {
            const int s = ((kk >> 2) & 7) << 2;
            const float4 a0 = *reinterpret_cast<const float4*>(&AT[kk * 128 + ((8 * tr) ^ s)]);
            const float4 a1 = *reinterpret_cast<const float4*>(&AT[kk * 128 + ((8 * tr + 4) ^ s)]);
            const float4 b0 = *reinterpret_cast<const float4*>(&WT[kk * 128 + 4 * tc]);
            const float4 b1 = *reinterpret_cast<const float4*>(&WT[kk * 128 + 64 + 4 * tc]);
            const float av[8] = {a0.x, a0.y, a0.z, a0.w, a1.x, a1.y, a1.z, a1.w};
            const float bv[8] = {b0.x, b0.y, b0.z, b0.w, b1.x, b1.y, b1.z, b1.w};
#pragma unroll
            for (int i = 0; i < 8; ++i)
#pragma unroll
                for (int j = 0; j < 8; ++j)
                    acc[i][j] = fmaf(av[i], bv[j], acc[i][j]);
        }
        __syncthreads();
    }

    // ---- epilogue ----
    const float scale = SCALE ? scale_ptr[0] : 1.0f;
    float bloc[8];
#pragma unroll
    for (int j = 0; j < 4; ++j) {
        bloc[j]     = bias[4 * tc + j];
        bloc[4 + j] = bias[64 + 4 * tc + j];
    }
    float ssq = 0.f;
#pragma unroll
    for (int i = 0; i < 8; ++i) {
        const int row = brow + 8 * tr + i;
        if (row < M) {
            float4 o0, o1;
            float v;
            v = fmaxf(fmaf(acc[i][0], scale, bloc[0]), 0.f); o0.x = v; if (SUMSQ) ssq += v * v;
            v = fmaxf(fmaf(acc[i][1], scale, bloc[1]), 0.f); o0.y = v; if (SUMSQ) ssq += v * v;
            v = fmaxf(fmaf(acc[i][2], scale, bloc[2]), 0.f); o0.z = v; if (SUMSQ) ssq += v * v;
            v = fmaxf(fmaf(acc[i][3], scale, bloc[3]), 0.f); o0.w = v; if (SUMSQ) ssq += v * v;
            v = fmaxf(fmaf(acc[i][4], scale, bloc[4]), 0.f); o1.x = v; if (SUMSQ) ssq += v * v;
            v = fmaxf(fmaf(acc[i][5], scale, bloc[5]), 0.f); o1.y = v; if (SUMSQ) ssq += v * v;
            v = fmaxf(fmaf(acc[i][6], scale, bloc[6]), 0.f); o1.z = v; if (SUMSQ) ssq += v * v;
            v = fmaxf(fmaf(acc[i][7], scale, bloc[7]), 0.f); o1.w = v; if (SUMSQ) ssq += v * v;
            *reinterpret_cast<float4*>(&out[(size_t)row * ldo + 4 * tc])      = o0;
            *reinterpret_cast<float4*>(&out[(size_t)row * ldo + 64 + 4 * tc]) = o1;
        }
    }

    if (SUMSQ) {
        __syncthreads();                 // AT free after compute loop
        float* red = AT;
        red[tid] = ssq;
        __syncthreads();
        for (int st = 128; st > 0; st >>= 1) {
            if (tid < st) red[tid] += red[tid + st];
            __syncthreads();
        }
        if (tid == 0) partials[blockIdx.x] = red[0];
    }
}

// ---------------------------------------------------------------------------
// agg[n][:] = sum_t alpha[n,t] * H[neigh_ids[n,t]][:]   (written to out, ld=256)
// block = 256 threads = 8 rows x 32 lanes of float4
// ---------------------------------------------------------------------------
__global__ __launch_bounds__(256)
void agg_kernel(const float* __restrict__ H,
                const int* __restrict__ nids,
                const float* __restrict__ alpha,
                float* __restrict__ out,   // points at nh_agg + 128
                int N)
{
    const int lr = threadIdx.x >> 5;   // 0..7
    const int c4 = threadIdx.x & 31;   // float4 column
    const int n  = blockIdx.x * 8 + lr;
    if (n >= N) return;

    const int*   idp = &nids[n * 20];
    const float* alp = &alpha[n * 20];
    float ax = 0.f, ay = 0.f, az = 0.f, aw = 0.f;
#pragma unroll
    for (int t = 0; t < 20; ++t) {
        const int   id = idp[t];
        const float al = alp[t];
        const float4 h = *reinterpret_cast<const float4*>(&H[(size_t)id * 128 + 4 * c4]);
        ax = fmaf(al, h.x, ax);
        ay = fmaf(al, h.y, ay);
        az = fmaf(al, h.z, az);
        aw = fmaf(al, h.w, aw);
    }
    float4 o; o.x = ax; o.y = ay; o.z = az; o.w = aw;
    *reinterpret_cast<float4*>(&out[(size_t)n * 256 + 4 * c4]) = o;
}

// ---------------------------------------------------------------------------
// Fallback agg (no H buffer): direct per-neighbor matmul. Slow but correct.
// ---------------------------------------------------------------------------
__global__ __launch_bounds__(256, 2)
void direct_agg(const float* __restrict__ table,
                const float* __restrict__ Wn,
                const float* __restrict__ bn,
                const int* __restrict__ nids,
                const float* __restrict__ alpha,
                float* __restrict__ outb,   // nh_agg + 128
                int N)
{
    __shared__ float Wl[128 * 128];   // 64 KB
#pragma unroll
    for (int it = 0; it < 16; ++it) {
        int idx = it * 256 + threadIdx.x;
        reinterpret_cast<float4*>(Wl)[idx] = reinterpret_cast<const float4*>(Wn)[idx];
    }
    __syncthreads();

    const int nn = threadIdx.x >> 7;   // 0/1
    const int u  = threadIdx.x & 127;
    const float bnu = bn[u];
    for (int p = blockIdx.x; 2 * p < N; p += gridDim.x) {
        const int n = 2 * p + nn;
        if (n < N) {
            float acc = 0.f;
            for (int t = 0; t < 20; ++t) {
                const int   id = nids[n * 20 + t];
                const float al = alpha[n * 20 + t];
                const float* xr = &table[(size_t)id * 128];
                float dot = 0.f;
#pragma unroll 16
                for (int k = 0; k < 128; ++k)
                    dot = fmaf(xr[k], Wl[k * 128 + u], dot);
                acc = fmaf(al, fmaxf(dot + bnu, 0.f), acc);
            }
            outb[(size_t)n * 256 + u] = acc;
        }
    }
}

// ---------------------------------------------------------------------------
// Reduce block partials -> 1/sqrt(sum)  (deterministic, no atomics)
// ---------------------------------------------------------------------------
__global__ void reduce_norm(const float* __restrict__ partials, int n,
                            float* __restrict__ scale)
{
    __shared__ float red[256];
    float s = 0.f;
    for (int i = threadIdx.x; i < n; i += 256) s += partials[i];
    red[threadIdx.x] = s;
    __syncthreads();
    for (int st = 128; st > 0; st >>= 1) {
        if (threadIdx.x < st) red[threadIdx.x] += red[threadIdx.x + st];
        __syncthreads();
    }
    if (threadIdx.x == 0) scale[0] = 1.0f / sqrtf(red[0]);
}

// ---------------------------------------------------------------------------
extern "C" void kernel_launch(void* const* d_in, const int* in_sizes, int n_in,
                              void* d_out, int out_size, void* d_ws, size_t ws_size,
                              hipStream_t stream)
{
    const int*   node_ids  = (const int*)  d_in[0];
    const int*   neigh_ids = (const int*)  d_in[1];
    const float* alpha     = (const float*)d_in[2];
    const float* table     = (const float*)d_in[3];
    const float* Wq        = (const float*)d_in[4];
    const float* bq        = (const float*)d_in[5];
    const float* Wn        = (const float*)d_in[6];
    const float* bn        = (const float*)d_in[7];
    const float* Ww        = (const float*)d_in[8];
    const float* bw        = (const float*)d_in[9];
    const float* Wg        = (const float*)d_in[10];
    const float* bg        = (const float*)d_in[11];

    const int N = in_sizes[0];            // 50000
    const int V = in_sizes[3] / 128;      // 200000
    float* out = (float*)d_out;

    const size_t H_f  = (size_t)V * 128;
    const size_t nh_f = (size_t)N * 256;
    const size_t need_full = (H_f + nh_f + 1024) * sizeof(float);
    const size_t need_fb   = (nh_f + 1024) * sizeof(float);

    const int nblkN = (N + 127) / 128;

    if (ws_size >= need_full) {
        float* H        = (float*)d_ws;
        float* nh       = H + H_f;                 // [N][256] = [node_h | agg]
        float* partials = nh + nh_f;
        float* scale    = partials + 512;
        const int nblkV = (V + 127) / 128;

        // 1) H = relu(table @ Wn + bn)          [V,128]
        gemm_relu<128, false, false, false><<<nblkV, 256, 0, stream>>>(
            table, 128, nullptr, Wn, bn, H, 128, V, nullptr, nullptr);
        // 2) node_h = relu(table[node_ids] @ Wq + bq) -> nh[:, 0:128]
        gemm_relu<128, true, false, false><<<nblkN, 256, 0, stream>>>(
            table, 128, node_ids, Wq, bq, nh, 256, N, nullptr, nullptr);
        // 3) agg -> nh[:, 128:256]
        agg_kernel<<<(N + 7) / 8, 256, 0, stream>>>(H, neigh_ids, alpha, nh + 128, N);
        // 4) emb = relu(nh @ Ww + bw) -> d_out, + sumsq partials
        gemm_relu<256, false, true, false><<<nblkN, 256, 0, stream>>>(
            nh, 256, nullptr, Ww, bw, out, 128, N, partials, nullptr);
        // 5) scale = 1/||emb||_F
        reduce_norm<<<1, 256, 0, stream>>>(partials, nblkN, scale);
        // 6) out = relu(emb*scale @ Wg + bg)   (in place; block reads own rows first)
        gemm_relu<128, false, false, true><<<nblkN, 256, 0, stream>>>(
            out, 128, nullptr, Wg, bg, out, 128, N, nullptr, scale);
    } else if (ws_size >= need_fb) {
        float* nh       = (float*)d_ws;
        float* partials = nh + nh_f;
        float* scale    = partials + 512;

        gemm_relu<128, true, false, false><<<nblkN, 256, 0, stream>>>(
            table, 128, node_ids, Wq, bq, nh, 256, N, nullptr, nullptr);
        direct_agg<<<2048, 256, 0, stream>>>(table, Wn, bn, neigh_ids, alpha, nh + 128, N);
        gemm_relu<256, false, true, false><<<nblkN, 256, 0, stream>>>(
            nh, 256, nullptr, Ww, bw, out, 128, N, partials, nullptr);
        reduce_norm<<<1, 256, 0, stream>>>(partials, nblkN, scale);
        gemm_relu<128, false, false, true><<<nblkN, 256, 0, stream>>>(
            out, 128, nullptr, Wg, bg, out, 128, N, nullptr, scale);
    }
    // If ws is smaller than both paths, nothing we can do -- should not happen.
}

// Round 2
// 113.718 us; speedup vs baseline: 2.4623x; 2.4623x over previous
//
#include <hip/hip_runtime.h>
#include <math.h>

// PinSAGE fused pipeline, bf16-MFMA edition.
// Constants fixed by the reference: D=U=E=128, T=20. N, V from in_sizes.
//
// Pipeline:
//   0) prep:  WqT/WnT/WwT/WgT = bf16 transpose of weights (WT[n][k])
//   1) H    = relu(table @ Wn + bn)            -> bf16 [V][128]   (MFMA)
//   2) nodeh= relu(table[node_ids] @ Wq + bq)  -> bf16 nh[:,0:128] (MFMA, gather)
//   3) agg  = sum_t alpha * H[neigh]           -> bf16 nh[:,128:256] (gather-FMA)
//   4) emb  = relu(nh @ Ww + bw)               -> bf16 [N][128] + fp32 sumsq (MFMA)
//   5) scale= 1/sqrt(sum sumsq)
//   6) out  = relu(scale*(emb @ Wg) + bg)      -> fp32 d_out      (MFMA)

using f32x4  = __attribute__((ext_vector_type(4))) float;
using short8 = __attribute__((ext_vector_type(8))) short;   // 8 bf16 (4 VGPRs)

__device__ __forceinline__ ushort f2bf(float f) {
    uint u = __float_as_uint(f);
    return (ushort)((u + 0x7fffu + ((u >> 16) & 1u)) >> 16);   // RNE
}
__device__ __forceinline__ float bf2f(ushort h) {
    return __uint_as_float((uint)h << 16);
}

// ---------------------------------------------------------------------------
// Weight prep: WT[n][K] (bf16) = W[k][n].  Total 81920 elements over 4 mats.
// ---------------------------------------------------------------------------
__global__ __launch_bounds__(256)
void prep_weights(const float* __restrict__ Wq, const float* __restrict__ Wn,
                  const float* __restrict__ Ww, const float* __restrict__ Wg,
                  ushort* __restrict__ WqT, ushort* __restrict__ WnT,
                  ushort* __restrict__ WwT, ushort* __restrict__ WgT)
{
    int idx = blockIdx.x * 256 + threadIdx.x;   // grid = 320 blocks -> 81920
    const float* W; ushort* WT; int K; int j = idx;
    if (j < 16384)      { W = Wq; WT = WqT; K = 128; }
    else if (j < 32768) { W = Wn; WT = WnT; K = 128; j -= 16384; }
    else if (j < 65536) { W = Ww; WT = WwT; K = 256; j -= 32768; }
    else                { W = Wg; WT = WgT; K = 128; j -= 65536; }
    int n = j & 127, k = j >> 7;                // W row-major [K][128]: j = k*128+n
    WT[(size_t)n * K + k] = f2bf(W[j]);
}

// ---------------------------------------------------------------------------
// MFMA GEMM: out[r][c] = relu( scale*(A[g(r)] @ W)[c] + bias[c] ), N-dim = 128.
// 128x128 tile / block, 256 thr = 4 waves, wave w owns rows 32w..32w+31
// (2 row-frags x 8 col-frags of 16x16x32 bf16 MFMA). K-chunks of 128.
// LDS: A-tile bf16 [128][128] + B-tile bf16 [128][128], XOR-swizzled
// (byte ^= (row&7)<<4) on both write and read sides.
// ---------------------------------------------------------------------------
template<int KTOT, bool GATHER, bool ABF16, bool SUMSQ, bool SCALE, bool OUTBF16>
__global__ __launch_bounds__(256, 2)
void mfma_gemm(const void* __restrict__ Av, int lda,
               const int* __restrict__ gidx,
               const ushort* __restrict__ WT,   // [128][KTOT] bf16, pre-transposed
               const float* __restrict__ bias,
               void* __restrict__ outv, int ldo, int M,
               float* __restrict__ partials,
               const float* __restrict__ scale_ptr)
{
    __shared__ __align__(16) char smem[65536];  // A: [0,32K)  B: [32K,64K)
    __shared__ float red[256];
    char* Bbase = smem + 32768;

    const int tid = threadIdx.x;
    const int w   = tid >> 6;
    const int l   = tid & 63;
    const int l16 = l & 15, lh = l >> 4;
    const int brow = blockIdx.x * 128;

    f32x4 acc[2][8];
#pragma unroll
    for (int fr = 0; fr < 2; ++fr)
#pragma unroll
        for (int fc = 0; fc < 8; ++fc)
#pragma unroll
            for (int i = 0; i < 4; ++i) acc[fr][fc][i] = 0.f;

    for (int k0 = 0; k0 < KTOT; k0 += 128) {
        // ---- stage A chunk (128 rows x 128 k) as bf16, swizzled ----
        if (ABF16) {
            const ushort* A = (const ushort*)Av;
#pragma unroll
            for (int it = 0; it < 8; ++it) {
                int idx = it * 256 + tid;       // 0..2047
                int r = idx >> 4, o = idx & 15;
                int row = brow + r; int grow = (row < M) ? row : (M - 1);
                if (GATHER) grow = gidx[grow];
                uint4 v = *reinterpret_cast<const uint4*>(&A[(size_t)grow * lda + k0 + 8 * o]);
                *reinterpret_cast<uint4*>(smem + r * 256 + ((16 * o) ^ ((r & 7) << 4))) = v;
            }
        } else {
            const float* A = (const float*)Av;
#pragma unroll
            for (int it = 0; it < 16; ++it) {
                int idx = it * 256 + tid;       // 0..4095
                int r = idx >> 5, q = idx & 31;
                int row = brow + r; int grow = (row < M) ? row : (M - 1);
                if (GATHER) grow = gidx[grow];
                float4 v = *reinterpret_cast<const float4*>(&A[(size_t)grow * lda + k0 + 4 * q]);
                uint2 p;
                p.x = (uint)f2bf(v.x) | ((uint)f2bf(v.y) << 16);
                p.y = (uint)f2bf(v.z) | ((uint)f2bf(v.w) << 16);
                *reinterpret_cast<uint2*>(smem + r * 256 + ((8 * q) ^ ((r & 7) << 4))) = p;
            }
        }
        // ---- stage B chunk: WT[n][k0..k0+127] bf16, swizzled on n ----
#pragma unroll
        for (int it = 0; it < 8; ++it) {
            int idx = it * 256 + tid;           // 0..2047
            int n = idx >> 4, o = idx & 15;
            uint4 v = *reinterpret_cast<const uint4*>(&WT[(size_t)n * KTOT + k0 + 8 * o]);
            *reinterpret_cast<uint4*>(Bbase + n * 256 + ((16 * o) ^ ((n & 7) << 4))) = v;
        }
        __syncthreads();

        // ---- MFMA: 4 k-steps of 32 ----
        const int r0 = 32 * w + l16;            // frag row for fr=0
        const int r1 = r0 + 16;                 // frag row for fr=1
#pragma unroll
        for (int ks = 0; ks < 4; ++ks) {
            const int kb = 64 * ks + 16 * lh;   // byte offset of this lane's 8 bf16
            short8 a0 = *reinterpret_cast<const short8*>(
                smem + r0 * 256 + (kb ^ ((r0 & 7) << 4)));
            short8 a1 = *reinterpret_cast<const short8*>(
                smem + r1 * 256 + (kb ^ ((r1 & 7) << 4)));
#pragma unroll
            for (int fc = 0; fc < 8; ++fc) {
                const int nn = 16 * fc + l16;
                short8 b = *reinterpret_cast<const short8*>(
                    Bbase + nn * 256 + (kb ^ ((nn & 7) << 4)));
                acc[0][fc] = __builtin_amdgcn_mfma_f32_16x16x32_bf16(a0, b, acc[0][fc], 0, 0, 0);
                acc[1][fc] = __builtin_amdgcn_mfma_f32_16x16x32_bf16(a1, b, acc[1][fc], 0, 0, 0);
            }
        }
        __syncthreads();
    }

    // ---- epilogue: scale+bias+relu, sumsq, repack via LDS, coalesced store ----
    const float scale = SCALE ? scale_ptr[0] : 1.0f;
    float bloc[8];
#pragma unroll
    for (int fc = 0; fc < 8; ++fc) bloc[fc] = bias[16 * fc + l16];

    float ssq = 0.f;
#pragma unroll
    for (int fr = 0; fr < 2; ++fr)
#pragma unroll
        for (int fc = 0; fc < 8; ++fc)
#pragma unroll
            for (int i = 0; i < 4; ++i) {
                const int r   = 32 * w + 16 * fr + 4 * lh + i;   // C/D: row=(l>>4)*4+i
                const int col = 16 * fc + l16;                   //      col=l&15
                float v = fmaxf(fmaf(acc[fr][fc][i], scale, bloc[fc]), 0.f);
                if (SUMSQ) { if (brow + r < M) ssq += v * v; }
                if (OUTBF16) ((ushort*)smem)[r * 128 + col] = f2bf(v);
                else         ((float*)smem)[r * 128 + col] = v;
            }
    __syncthreads();

    if (OUTBF16) {
        ushort* out = (ushort*)outv;
#pragma unroll
        for (int it = 0; it < 8; ++it) {
            int idx = it * 256 + tid;
            int r = idx >> 4, o = idx & 15;
            if (brow + r < M)
                *reinterpret_cast<uint4*>(&out[(size_t)(brow + r) * ldo + 8 * o]) =
                    *reinterpret_cast<const uint4*>((ushort*)smem + r * 128 + 8 * o);
        }
    } else {
        float* out = (float*)outv;
#pragma unroll
        for (int it = 0; it < 16; ++it) {
            int idx = it * 256 + tid;
            int r = idx >> 5, q = idx & 31;
            if (brow + r < M)
                *reinterpret_cast<float4*>(&out[(size_t)(brow + r) * ldo + 4 * q]) =
                    *reinterpret_cast<const float4*>((float*)smem + r * 128 + 4 * q);
        }
    }

    if (SUMSQ) {
        red[tid] = ssq;
        __syncthreads();
        for (int st = 128; st > 0; st >>= 1) {
            if (tid < st) red[tid] += red[tid + st];
            __syncthreads();
        }
        if (tid == 0) partials[blockIdx.x] = red[0];
    }
}

// ---------------------------------------------------------------------------
// agg[n][:] = sum_t alpha[n,t] * H[neigh_ids[n,t]][:]   (H bf16, out bf16)
// 256 thr = 16 rows x 16 lanes of bf16x8 (16 B each).
// ---------------------------------------------------------------------------
__global__ __launch_bounds__(256)
void agg_bf16(const ushort* __restrict__ H,
              const int* __restrict__ nids,
              const float* __restrict__ alpha,
              ushort* __restrict__ outb,     // points at nh + 128, row stride 256
              int N)
{
    const int n   = blockIdx.x * 16 + (threadIdx.x >> 4);
    const int l16 = threadIdx.x & 15;
    if (n >= N) return;

    const int*   idp = &nids[n * 20];
    const float* alp = &alpha[n * 20];
    float a[8];
#pragma unroll
    for (int j = 0; j < 8; ++j) a[j] = 0.f;

#pragma unroll
    for (int t = 0; t < 20; ++t) {
        const int   id = idp[t];
        const float al = alp[t];
        uint4 h = *reinterpret_cast<const uint4*>(&H[(size_t)id * 128 + 8 * l16]);
        a[0] = fmaf(al, bf2f((ushort)(h.x & 0xffff)), a[0]);
        a[1] = fmaf(al, bf2f((ushort)(h.x >> 16)),    a[1]);
        a[2] = fmaf(al, bf2f((ushort)(h.y & 0xffff)), a[2]);
        a[3] = fmaf(al, bf2f((ushort)(h.y >> 16)),    a[3]);
        a[4] = fmaf(al, bf2f((ushort)(h.z & 0xffff)), a[4]);
        a[5] = fmaf(al, bf2f((ushort)(h.z >> 16)),    a[5]);
        a[6] = fmaf(al, bf2f((ushort)(h.w & 0xffff)), a[6]);
        a[7] = fmaf(al, bf2f((ushort)(h.w >> 16)),    a[7]);
    }
    uint4 p;
    p.x = (uint)f2bf(a[0]) | ((uint)f2bf(a[1]) << 16);
    p.y = (uint)f2bf(a[2]) | ((uint)f2bf(a[3]) << 16);
    p.z = (uint)f2bf(a[4]) | ((uint)f2bf(a[5]) << 16);
    p.w = (uint)f2bf(a[6]) | ((uint)f2bf(a[7]) << 16);
    *reinterpret_cast<uint4*>(&outb[(size_t)n * 256 + 8 * l16]) = p;
}

// ---------------------------------------------------------------------------
__global__ void reduce_norm(const float* __restrict__ partials, int n,
                            float* __restrict__ scale)
{
    __shared__ float red[256];
    float s = 0.f;
    for (int i = threadIdx.x; i < n; i += 256) s += partials[i];
    red[threadIdx.x] = s;
    __syncthreads();
    for (int st = 128; st > 0; st >>= 1) {
        if (threadIdx.x < st) red[threadIdx.x] += red[threadIdx.x + st];
        __syncthreads();
    }
    if (threadIdx.x == 0) scale[0] = 1.0f / sqrtf(red[0]);
}

// ---------------------------------------------------------------------------
extern "C" void kernel_launch(void* const* d_in, const int* in_sizes, int n_in,
                              void* d_out, int out_size, void* d_ws, size_t ws_size,
                              hipStream_t stream)
{
    const int*   node_ids  = (const int*)  d_in[0];
    const int*   neigh_ids = (const int*)  d_in[1];
    const float* alpha     = (const float*)d_in[2];
    const float* table     = (const float*)d_in[3];
    const float* Wq        = (const float*)d_in[4];
    const float* bq        = (const float*)d_in[5];
    const float* Wn        = (const float*)d_in[6];
    const float* bn        = (const float*)d_in[7];
    const float* Ww        = (const float*)d_in[8];
    const float* bw        = (const float*)d_in[9];
    const float* Wg        = (const float*)d_in[10];
    const float* bg        = (const float*)d_in[11];

    const int N = in_sizes[0];            // 50000
    const int V = in_sizes[3] / 128;      // 200000
    float* out = (float*)d_out;

    // workspace layout (all bf16 except partials/scale)
    ushort* H    = (ushort*)d_ws;                 // [V][128]
    ushort* nh   = H    + (size_t)V * 128;        // [N][256] = [node_h | agg]
    ushort* embb = nh   + (size_t)N * 256;        // [N][128]
    ushort* WqT  = embb + (size_t)N * 128;        // [128][128]
    ushort* WnT  = WqT  + 16384;                  // [128][128]
    ushort* WwT  = WnT  + 16384;                  // [128][256]
    ushort* WgT  = WwT  + 32768;                  // [128][128]
    float*  partials = (float*)(WgT + 16384);     // 512
    float*  scale    = partials + 512;

    const size_t need = (size_t)((char*)(scale + 16) - (char*)d_ws);
    if (ws_size < need) return;   // should not happen (ws proven >=154MB, need ~90MB)

    const int nblkN = (N + 127) / 128;
    const int nblkV = (V + 127) / 128;

    // 0) weights -> bf16 transposed
    prep_weights<<<320, 256, 0, stream>>>(Wq, Wn, Ww, Wg, WqT, WnT, WwT, WgT);
    // 1) H = relu(table @ Wn + bn) -> bf16
    mfma_gemm<128, false, false, false, false, true><<<nblkV, 256, 0, stream>>>(
        table, 128, nullptr, WnT, bn, H, 128, V, nullptr, nullptr);
    // 2) node_h = relu(table[node_ids] @ Wq + bq) -> nh[:, 0:128]
    mfma_gemm<128, true, false, false, false, true><<<nblkN, 256, 0, stream>>>(
        table, 128, node_ids, WqT, bq, nh, 256, N, nullptr, nullptr);
    // 3) agg -> nh[:, 128:256]
    agg_bf16<<<(N + 15) / 16, 256, 0, stream>>>(H, neigh_ids, alpha, nh + 128, N);
    // 4) emb = relu(nh @ Ww + bw) -> bf16 embb, + fp32 sumsq partials
    mfma_gemm<256, false, true, true, false, true><<<nblkN, 256, 0, stream>>>(
        nh, 256, nullptr, WwT, bw, embb, 128, N, partials, nullptr);
    // 5) scale = 1/||emb||_F
    reduce_norm<<<1, 256, 0, stream>>>(partials, nblkN, scale);
    // 6) out = relu(scale*(emb @ Wg) + bg) -> fp32 d_out
    mfma_gemm<128, false, true, false, true, false><<<nblkN, 256, 0, stream>>>(
        embb, 128, nullptr, WgT, bg, out, 128, N, nullptr, scale);
}